// Round 1
// baseline (8648.511 us; speedup 1.0000x reference)
//
#include <hip/hip_runtime.h>

// Problem constants
#define BB 32      // batch
#define SS 512     // seq len
#define II 512     // input size
#define HH 512     // hidden
#define GG 2048    // 4*H

typedef unsigned short u16;
typedef unsigned int   u32;

typedef __attribute__((ext_vector_type(8))) short bf16x8;
typedef __attribute__((ext_vector_type(4))) float f32x4;

__device__ __forceinline__ float b2f(u16 h) {
    return __uint_as_float(((u32)h) << 16);
}
__device__ __forceinline__ u16 f2b(float f) {  // RNE f32 -> bf16
    u32 u = __float_as_uint(f);
    u32 r = (u + 0x7FFFu + ((u >> 16) & 1u)) >> 16;
    return (u16)r;
}

// ---------------- convert x: [B][S][I] f32 -> [S][B][I] bf16 ----------------
__global__ void k_convert_x(const float* __restrict__ x, u16* __restrict__ xbf) {
    const int n4 = BB * SS * II / 4;  // 2,097,152
    for (int e4 = blockIdx.x * blockDim.x + threadIdx.x; e4 < n4;
         e4 += gridDim.x * blockDim.x) {
        int e = e4 * 4;
        int s = e >> 14;         // / (B*I = 16384)
        int b = (e >> 9) & 31;
        int i = e & 511;
        float4 v = *(const float4*)(x + (size_t)b * (SS * II) + (size_t)s * II + i);
        ushort4 o;
        o.x = f2b(v.x); o.y = f2b(v.y); o.z = f2b(v.z); o.w = f2b(v.w);
        *(ushort4*)(xbf + (size_t)s * (BB * II) + (size_t)b * II + i) = o;
    }
}

// ---------------- generic f32 -> bf16 cast ----------------
__global__ void k_cast(const float* __restrict__ src, u16* __restrict__ dst, int n4) {
    for (int e4 = blockIdx.x * blockDim.x + threadIdx.x; e4 < n4;
         e4 += gridDim.x * blockDim.x) {
        float4 v = *(const float4*)(src + (size_t)e4 * 4);
        ushort4 o;
        o.x = f2b(v.x); o.y = f2b(v.y); o.z = f2b(v.z); o.w = f2b(v.w);
        *(ushort4*)(dst + (size_t)e4 * 4) = o;
    }
}

// ---------------- input projection GEMM (MFMA bf16) ----------------
// xp[m][n] = sum_k A[m][k] * W[n][k] + b_ih[n] + b_hh[n]
// A: [16384][K] bf16 (rows m = s*32+b), W: [2048][K] bf16. Output bf16 [16384][2048].
#define PJ_LD 40   // padded LDS row stride (bf16 elems), 80B, 16B-aligned

__launch_bounds__(256)
__global__ void k_proj(const u16* __restrict__ A,
                       const u16* __restrict__ Wf, const u16* __restrict__ Wb,
                       const float* __restrict__ bihf, const float* __restrict__ bhhf,
                       const float* __restrict__ bihb, const float* __restrict__ bhhb,
                       u16* __restrict__ xpf, u16* __restrict__ xpb,
                       int K) {
    const int dir = blockIdx.z;
    const u16* W = dir ? Wb : Wf;
    const float* bih = dir ? bihb : bihf;
    const float* bhh = dir ? bhhb : bhhf;
    u16* xp = dir ? xpb : xpf;

    __shared__ __align__(16) u16 As[64 * PJ_LD];
    __shared__ __align__(16) u16 Ws[64 * PJ_LD];

    const int t    = threadIdx.x;
    const int lane = t & 63;
    const int wave = t >> 6;
    const int wm   = wave >> 1, wn = wave & 1;
    const int m0   = blockIdx.x * 64;
    const int n0   = blockIdx.y * 64;

    const int srow = t >> 2;           // 0..63
    const int sseg = (t & 3) * 8;      // 0,8,16,24 (bf16 elems)

    f32x4 acc[2][2] = {};

    for (int kt = 0; kt < K; kt += 32) {
        __syncthreads();
        *(bf16x8*)&As[srow * PJ_LD + sseg] =
            *(const bf16x8*)(A + (size_t)(m0 + srow) * K + kt + sseg);
        *(bf16x8*)&Ws[srow * PJ_LD + sseg] =
            *(const bf16x8*)(W + (size_t)(n0 + srow) * K + kt + sseg);
        __syncthreads();

        const int koff = (lane >> 4) * 8;
        bf16x8 a0 = *(const bf16x8*)&As[(wm * 32 +  0 + (lane & 15)) * PJ_LD + koff];
        bf16x8 a1 = *(const bf16x8*)&As[(wm * 32 + 16 + (lane & 15)) * PJ_LD + koff];
        bf16x8 b0 = *(const bf16x8*)&Ws[(wn * 32 +  0 + (lane & 15)) * PJ_LD + koff];
        bf16x8 b1 = *(const bf16x8*)&Ws[(wn * 32 + 16 + (lane & 15)) * PJ_LD + koff];
        acc[0][0] = __builtin_amdgcn_mfma_f32_16x16x32_bf16(a0, b0, acc[0][0], 0, 0, 0);
        acc[0][1] = __builtin_amdgcn_mfma_f32_16x16x32_bf16(a0, b1, acc[0][1], 0, 0, 0);
        acc[1][0] = __builtin_amdgcn_mfma_f32_16x16x32_bf16(a1, b0, acc[1][0], 0, 0, 0);
        acc[1][1] = __builtin_amdgcn_mfma_f32_16x16x32_bf16(a1, b1, acc[1][1], 0, 0, 0);
    }

    // Epilogue: C/D layout col = lane&15, row = (lane>>4)*4 + r  [guide §3]
    #pragma unroll
    for (int ni = 0; ni < 2; ni++) {
        int n = n0 + wn * 32 + ni * 16 + (lane & 15);
        float bias = bih[n] + bhh[n];
        #pragma unroll
        for (int mi = 0; mi < 2; mi++) {
            #pragma unroll
            for (int r = 0; r < 4; r++) {
                int m = m0 + wm * 32 + mi * 16 + (lane >> 4) * 4 + r;
                xp[(size_t)m * GG + n] = f2b(acc[mi][ni][r] + bias);
            }
        }
    }
}

// ---------------- one recurrence step (both directions) ----------------
// grid = 256 WGs x 256 thr. WG: dir = bid>>7, wg = bid&127 owns h-cols c0..c0+3
// (i.e. gate rows q*512 + c0 + jj for q in 0..3). K = 512 dot per gate output.
#define RST 524    // LDS row stride in bf16 elems (1048B; 8B aligned; 2-way banks)

__launch_bounds__(256)
__global__ void k_rec(const u16* __restrict__ xpf, const u16* __restrict__ xpb,
                      const u16* __restrict__ Whf, const u16* __restrict__ Whb,
                      const u16* __restrict__ h_prev,  // [2dir][32][512] bf16
                      u16* __restrict__ h_next,
                      float* __restrict__ c_state,     // [2dir][32][512] f32
                      u16* __restrict__ hs0,           // layer0 out [s][b][1024] bf16
                      float* __restrict__ out,         // layer1 out [b][s][1024] f32
                      float* __restrict__ fin,         // d_out + 16777216
                      int step, int layer) {
    const int bid = blockIdx.x;
    const int dir = bid >> 7;
    const int wg  = bid & 127;
    const int c0  = wg * 4;
    const int s   = dir ? (SS - 1 - step) : step;
    const u16* xp = dir ? xpb : xpf;
    const u16* Wh = dir ? Whb : Whf;

    __shared__ __align__(16) u16 Wl[16 * RST];
    __shared__ __align__(16) u16 hl[32 * RST];
    __shared__ float xq[32 * 16];
    __shared__ float pp[4 * 16 * 32];

    const int t = threadIdx.x;

    // stage W_hh rows (16 rows x 512 bf16)
    {
        int r = t >> 4;            // 0..15
        int seg = t & 15;          // 16 segs of 32 elems
        int grow = (r >> 2) * 512 + c0 + (r & 3);
        const u16* src = Wh + (size_t)grow * 512 + seg * 32;
        u16* dst = &Wl[r * RST + seg * 32];
        #pragma unroll
        for (int i = 0; i < 8; i++)
            *(ushort4*)(dst + i * 4) = *(const ushort4*)(src + i * 4);
    }
    // stage h_prev (32 x 512 bf16)
    {
        const u16* hsrc = h_prev + dir * (32 * 512);
        #pragma unroll
        for (int i = 0; i < 16; i++) {
            int id = i * 256 + t;
            int b  = id >> 7;      // /128 ushort4 per row
            int kq = id & 127;
            *(ushort4*)&hl[b * RST + kq * 4] = *(const ushort4*)(hsrc + b * 512 + kq * 4);
        }
    }
    // stage xp slice (32 b x 16 cols) and c state
    float cv = 0.f;
    if (t < 128) {
        int b = t & 31, q = t >> 5;
        ushort4 v = *(const ushort4*)(xp + (size_t)s * (BB * GG) + (size_t)b * GG + q * 512 + c0);
        xq[b * 16 + q * 4 + 0] = b2f(v.x);
        xq[b * 16 + q * 4 + 1] = b2f(v.y);
        xq[b * 16 + q * 4 + 2] = b2f(v.z);
        xq[b * 16 + q * 4 + 3] = b2f(v.w);
        // c for (b, jj=q)
        cv = c_state[dir * (32 * 512) + b * 512 + c0 + q];
    }
    __syncthreads();

    // dot phase: thread = (bg 0..7, cg 0..3, kc 0..7); 4c x 4b tile over 64 k
    {
        const int bg = t & 7, cg = (t >> 3) & 3, kc = t >> 5;
        float p[4][4] = {};
        const int kbase = kc * 64;
        #pragma unroll
        for (int kq = 0; kq < 16; kq++) {
            int k = kbase + kq * 4;
            float wf[4][4], hf[4][4];
            #pragma unroll
            for (int ci = 0; ci < 4; ci++) {
                uint2 u = *(const uint2*)&Wl[(cg * 4 + ci) * RST + k];
                wf[ci][0] = __uint_as_float(u.x << 16);
                wf[ci][1] = __uint_as_float(u.x & 0xffff0000u);
                wf[ci][2] = __uint_as_float(u.y << 16);
                wf[ci][3] = __uint_as_float(u.y & 0xffff0000u);
            }
            #pragma unroll
            for (int bi = 0; bi < 4; bi++) {
                uint2 u = *(const uint2*)&hl[(bg * 4 + bi) * RST + k];
                hf[bi][0] = __uint_as_float(u.x << 16);
                hf[bi][1] = __uint_as_float(u.x & 0xffff0000u);
                hf[bi][2] = __uint_as_float(u.y << 16);
                hf[bi][3] = __uint_as_float(u.y & 0xffff0000u);
            }
            #pragma unroll
            for (int ci = 0; ci < 4; ci++)
                #pragma unroll
                for (int bi = 0; bi < 4; bi++) {
                    p[ci][bi] += wf[ci][0] * hf[bi][0];
                    p[ci][bi] += wf[ci][1] * hf[bi][1];
                    p[ci][bi] += wf[ci][2] * hf[bi][2];
                    p[ci][bi] += wf[ci][3] * hf[bi][3];
                }
        }
        // pairwise reduce kc (t ^ 32) then store 4 partial planes
        #pragma unroll
        for (int ci = 0; ci < 4; ci++)
            #pragma unroll
            for (int bi = 0; bi < 4; bi++) {
                float v = p[ci][bi];
                v += __shfl_xor(v, 32, 64);
                p[ci][bi] = v;
            }
        if ((kc & 1) == 0) {
            int kk = kc >> 1;
            #pragma unroll
            for (int ci = 0; ci < 4; ci++)
                #pragma unroll
                for (int bi = 0; bi < 4; bi++)
                    pp[kk * 512 + (cg * 4 + ci) * 32 + bg * 4 + bi] = p[ci][bi];
        }
    }
    __syncthreads();

    // epilogue: 128 threads -> (b, jj)
    if (t < 128) {
        int b = t & 31, jj = t >> 5;
        float g4[4];
        #pragma unroll
        for (int q = 0; q < 4; q++) {
            int c = q * 4 + jj;
            float v = xq[b * 16 + c];
            #pragma unroll
            for (int kk = 0; kk < 4; kk++) v += pp[kk * 512 + c * 32 + b];
            g4[q] = v;
        }
        float ig = 1.f / (1.f + __expf(-g4[0]));
        float fg = 1.f / (1.f + __expf(-g4[1]));
        float gg = tanhf(g4[2]);
        float og = 1.f / (1.f + __expf(-g4[3]));
        float cn = fg * cv + ig * gg;
        float hn = og * tanhf(cn);
        int col = c0 + jj;
        c_state[dir * (32 * 512) + b * 512 + col] = cn;
        h_next[dir * (32 * 512) + b * 512 + col] = f2b(hn);
        if (layer == 0) {
            hs0[(size_t)s * (BB * 1024) + (size_t)b * 1024 + dir * 512 + col] = f2b(hn);
        } else {
            out[(size_t)b * (SS * 1024) + (size_t)s * 1024 + dir * 512 + col] = hn;
        }
        if (step == SS - 1) {
            int sl = layer * 2 + dir;
            fin[(size_t)sl * (32 * 512) + b * 512 + col] = hn;
            fin[65536 + (size_t)sl * (32 * 512) + b * 512 + col] = cn;
        }
    }
}

// ---------------- workspace layout (bytes) ----------------
#define OFF_XBF   ((size_t)0)                       // 16,777,216
#define OFF_HS0   ((size_t)16777216)                // 33,554,432
#define OFF_XPF   ((size_t)50331648)                // 67,108,864
#define OFF_XPB   ((size_t)117440512)               // 67,108,864
#define OFF_WIH0F ((size_t)184549376)               // 2,097,152
#define OFF_WIH0B ((size_t)186646528)
#define OFF_WIH1F ((size_t)188743680)               // 4,194,304
#define OFF_WIH1B ((size_t)192937984)
#define OFF_WHH0F ((size_t)197132288)               // 2,097,152 each
#define OFF_WHH0B ((size_t)199229440)
#define OFF_WHH1F ((size_t)201326592)
#define OFF_WHH1B ((size_t)203423744)
#define OFF_H     ((size_t)205520896)               // 131,072 (2pp x 2dir x 32 x 512 bf16)
#define OFF_C     ((size_t)205651968)               // 131,072 (2dir x 32 x 512 f32)

extern "C" void kernel_launch(void* const* d_in, const int* in_sizes, int n_in,
                              void* d_out, int out_size, void* d_ws, size_t ws_size,
                              hipStream_t stream) {
    const float* x      = (const float*)d_in[0];
    const float* wih0f  = (const float*)d_in[1];
    const float* whh0f  = (const float*)d_in[2];
    const float* bih0f  = (const float*)d_in[3];
    const float* bhh0f  = (const float*)d_in[4];
    const float* wih0b  = (const float*)d_in[5];
    const float* whh0b  = (const float*)d_in[6];
    const float* bih0b  = (const float*)d_in[7];
    const float* bhh0b  = (const float*)d_in[8];
    const float* wih1f  = (const float*)d_in[9];
    const float* whh1f  = (const float*)d_in[10];
    const float* bih1f  = (const float*)d_in[11];
    const float* bhh1f  = (const float*)d_in[12];
    const float* wih1b  = (const float*)d_in[13];
    const float* whh1b  = (const float*)d_in[14];
    const float* bih1b  = (const float*)d_in[15];
    const float* bhh1b  = (const float*)d_in[16];

    float* out = (float*)d_out;
    char* ws = (char*)d_ws;

    u16* xbf   = (u16*)(ws + OFF_XBF);
    u16* hs0   = (u16*)(ws + OFF_HS0);
    u16* xpf   = (u16*)(ws + OFF_XPF);
    u16* xpb   = (u16*)(ws + OFF_XPB);
    u16* bwih0f = (u16*)(ws + OFF_WIH0F);
    u16* bwih0b = (u16*)(ws + OFF_WIH0B);
    u16* bwih1f = (u16*)(ws + OFF_WIH1F);
    u16* bwih1b = (u16*)(ws + OFF_WIH1B);
    u16* bwhh0f = (u16*)(ws + OFF_WHH0F);
    u16* bwhh0b = (u16*)(ws + OFF_WHH0B);
    u16* bwhh1f = (u16*)(ws + OFF_WHH1F);
    u16* bwhh1b = (u16*)(ws + OFF_WHH1B);
    u16* hbuf  = (u16*)(ws + OFF_H);
    float* cbuf = (float*)(ws + OFF_C);
    float* fin = out + 16777216;  // final h stack, then c stack at +65536

    // zero h ping-pong + c state (layer 0)
    hipMemsetAsync(ws + OFF_H, 0, 262144, stream);

    // converts
    k_convert_x<<<1024, 256, 0, stream>>>(x, xbf);
    k_cast<<<512, 256, 0, stream>>>(wih0f, bwih0f, 2048 * 512 / 4);
    k_cast<<<512, 256, 0, stream>>>(wih0b, bwih0b, 2048 * 512 / 4);
    k_cast<<<512, 256, 0, stream>>>(wih1f, bwih1f, 2048 * 1024 / 4);
    k_cast<<<512, 256, 0, stream>>>(wih1b, bwih1b, 2048 * 1024 / 4);
    k_cast<<<512, 256, 0, stream>>>(whh0f, bwhh0f, 2048 * 512 / 4);
    k_cast<<<512, 256, 0, stream>>>(whh0b, bwhh0b, 2048 * 512 / 4);
    k_cast<<<512, 256, 0, stream>>>(whh1f, bwhh1f, 2048 * 512 / 4);
    k_cast<<<512, 256, 0, stream>>>(whh1b, bwhh1b, 2048 * 512 / 4);

    // layer 0
    k_proj<<<dim3(256, 32, 2), 256, 0, stream>>>(
        xbf, bwih0f, bwih0b, bih0f, bhh0f, bih0b, bhh0b, xpf, xpb, 512);
    for (int step = 0; step < SS; step++) {
        k_rec<<<256, 256, 0, stream>>>(
            xpf, xpb, bwhh0f, bwhh0b,
            hbuf + (size_t)(step & 1) * 32768,
            hbuf + (size_t)((step + 1) & 1) * 32768,
            cbuf, hs0, nullptr, fin, step, 0);
    }

    // layer 1
    hipMemsetAsync(ws + OFF_H, 0, 262144, stream);
    k_proj<<<dim3(256, 32, 2), 256, 0, stream>>>(
        hs0, bwih1f, bwih1b, bih1f, bhh1f, bih1b, bhh1b, xpf, xpb, 1024);
    for (int step = 0; step < SS; step++) {
        k_rec<<<256, 256, 0, stream>>>(
            xpf, xpb, bwhh1f, bwhh1b,
            hbuf + (size_t)(step & 1) * 32768,
            hbuf + (size_t)((step + 1) & 1) * 32768,
            cbuf, nullptr, out, fin, step, 1);
    }
}